// Round 1
// baseline (153.531 us; speedup 1.0000x reference)
//
#include <hip/hip_runtime.h>

// DurationEncoding: idx = searchsorted(bin_edges, time_value, side='left');
// out[i,:] = embed_table[idx[i],:]   (N=1M, NUM_EDGES=100, VOCAB=101, DIM=128, fp32)
//
// Memory-bound: output write (512 MB) dominates. One thread per float4 of
// output -> fully coalesced 16B/lane stores. Edges staged in LDS; 7-step
// uniform binary search (count is data-independent for fixed num_edges).

#define MAX_EDGES 128

__global__ __launch_bounds__(256) void duration_encoding_kernel(
    const float* __restrict__ time_value,
    const float* __restrict__ bin_edges,
    const float* __restrict__ embed_table,
    float* __restrict__ out,
    int n, int num_edges, int f4_per_row)
{
    __shared__ float s_edges[MAX_EDGES];
    for (int i = threadIdx.x; i < num_edges; i += blockDim.x)
        s_edges[i] = bin_edges[i];
    __syncthreads();

    const long long total  = (long long)n * f4_per_row;
    const long long stride = (long long)gridDim.x * blockDim.x;
    const float4* table4 = (const float4*)embed_table;
    float4* out4 = (float4*)out;

    for (long long j = (long long)blockIdx.x * blockDim.x + threadIdx.x;
         j < total; j += stride) {
        int row = (int)(j / f4_per_row);
        int c4  = (int)(j - (long long)row * f4_per_row);

        float v = time_value[row];   // broadcast within each 32-lane group

        // lower_bound: first pos where edges[pos] >= v  (side='left')
        int lo = 0, hi = num_edges;
        while (lo < hi) {
            int mid = (lo + hi) >> 1;
            if (s_edges[mid] < v) lo = mid + 1; else hi = mid;
        }

        out4[j] = table4[(long long)lo * f4_per_row + c4];
    }
}

extern "C" void kernel_launch(void* const* d_in, const int* in_sizes, int n_in,
                              void* d_out, int out_size, void* d_ws, size_t ws_size,
                              hipStream_t stream) {
    const float* time_value  = (const float*)d_in[0];
    const float* bin_edges   = (const float*)d_in[1];
    const float* embed_table = (const float*)d_in[2];
    float* out = (float*)d_out;

    const int n         = in_sizes[0];
    const int num_edges = in_sizes[1];
    const int dim       = out_size / n;        // 128
    const int f4_per_row = dim / 4;            // 32

    const int block = 256;
    const long long total = (long long)n * f4_per_row;
    long long blocks_needed = (total + block - 1) / block;
    int grid = (int)(blocks_needed < 2048 ? blocks_needed : 2048);

    duration_encoding_kernel<<<grid, block, 0, stream>>>(
        time_value, bin_edges, embed_table, out, n, num_edges, f4_per_row);
}